// Round 3
// baseline (157.057 us; speedup 1.0000x reference)
//
#include <hip/hip_runtime.h>

typedef __bf16 bf16x8 __attribute__((ext_vector_type(8)));
typedef __bf16 bf16x4 __attribute__((ext_vector_type(4)));
typedef float  f32x4  __attribute__((ext_vector_type(4)));
typedef float  f32x16 __attribute__((ext_vector_type(16)));

#define B_ 4
#define T_ 2048
#define H_ 8
#define D_ 64
#define E_ 512

// q scale: D^-0.5 * log2(e)  (softmax computed in exp2 domain)
#define QSCALE 0.18033688011112042f

// async global->LDS, 16B per lane. LDS dest is wave-uniform base + lane*16.
__device__ __forceinline__ void async_ld16(const __bf16* g, __bf16* lds) {
  __builtin_amdgcn_global_load_lds((const __attribute__((address_space(1))) void*)g,
                                   (__attribute__((address_space(3))) void*)lds,
                                   16, 0, 0);
}

// converts x, W_qkv (row-permuted to [which][h][d] order), W_0
__global__ void cvt_all(const float* __restrict__ x, const float* __restrict__ wq,
                        const float* __restrict__ w0, __bf16* __restrict__ xb,
                        __bf16* __restrict__ wqb, __bf16* __restrict__ w0b) {
  long i = (long)(blockIdx.x * 256 + threadIdx.x) * 8;
  const float* src; __bf16* dst; long roff, woff;
  if (i < 4194304L)      { src = x;  dst = xb;  roff = i; woff = i; }
  else if (i < 4980736L) {
    src = wq; dst = wqb; roff = i - 4194304L;
    // src row r = h*192 + d*3 + which  ->  dst row = which*512 + h*64 + d
    const int r = (int)(roff >> 9), c = (int)(roff & 511);
    const int h = r / 192, rem = r - h * 192;
    const int d = rem / 3, which = rem - d * 3;
    woff = (long)(which * 512 + h * 64 + d) * 512 + c;
  }
  else                   { src = w0; dst = w0b; roff = i - 4980736L; woff = roff; }
  float4 a = *(const float4*)(src + roff);
  float4 b = *(const float4*)(src + roff + 4);
  bf16x8 o;
  o[0] = (__bf16)a.x; o[1] = (__bf16)a.y; o[2] = (__bf16)a.z; o[3] = (__bf16)a.w;
  o[4] = (__bf16)b.x; o[5] = (__bf16)b.y; o[6] = (__bf16)b.z; o[7] = (__bf16)b.w;
  *(bf16x8*)(dst + woff) = o;
}

// C = A(MxK) * B(NxK)^T, K=512, TMx128 tile, 4 waves, 16x16x32 bf16 MFMA.
// Double-buffered staging, one barrier per K-step.
// MODE 0 (TM=128): qkv epilogue (W pre-permuted -> which = n0>>9 block-uniform).
// MODE 1: plain fp32 store, row-major MxN.
template<int MODE, int N, int TM>
__global__ __launch_bounds__(256, 2)
void gemm_bt(const __bf16* __restrict__ A, const __bf16* __restrict__ Bm,
             __bf16* __restrict__ o0, __bf16* __restrict__ o1, __bf16* __restrict__ o2,
             float* __restrict__ of) {
  constexpr int K = 512;
  constexpr int MI = TM / 32;                 // acc tiles in m per wave
  __shared__ __bf16 As[2][TM * 64];
  __shared__ __bf16 Bs[2][128 * 64];
  const int tid  = threadIdx.x;
  const int wave = tid >> 6, lane = tid & 63;
  const int l15 = lane & 15, l16 = lane >> 4;
  const int m0 = blockIdx.y * TM, n0 = blockIdx.x * 128;
  const int waveM = wave >> 1, waveN = wave & 1;
  const int srow = lane >> 3;
  const int sch  = (lane & 7) ^ srow;

  f32x4 acc[MI][4] = {};

  const __bf16* ag = A  + (size_t)(m0 + wave * 8 + srow) * K + sch * 8;
  const __bf16* bg = Bm + (size_t)(n0 + wave * 8 + srow) * K + sch * 8;

  auto stage = [&](int buf, int k0) {
#pragma unroll
    for (int it = 0; it < TM / 32; ++it)
      async_ld16(ag + (size_t)it * 32 * K + k0, &As[buf][(it * 32 + wave * 8) * 64]);
#pragma unroll
    for (int it = 0; it < 4; ++it)
      async_ld16(bg + (size_t)it * 32 * K + k0, &Bs[buf][(it * 32 + wave * 8) * 64]);
  };

  stage(0, 0);
#pragma unroll 2
  for (int kt = 0; kt < 8; ++kt) {
    __builtin_amdgcn_s_waitcnt(0);
    __syncthreads();
    if (kt < 7) stage((kt + 1) & 1, (kt + 1) * 64);
    const __bf16* Ac = As[kt & 1];
    const __bf16* Bc = Bs[kt & 1];
#pragma unroll
    for (int ks = 0; ks < 2; ++ks) {
      bf16x8 af[MI], bf[4];
      const int cb = ks * 4 + l16;
#pragma unroll
      for (int i = 0; i < MI; ++i) {
        const int rA = waveM * (TM / 2) + i * 16 + l15;
        af[i] = *(const bf16x8*)&Ac[rA * 64 + ((cb ^ (rA & 7)) * 8)];
      }
#pragma unroll
      for (int i = 0; i < 4; ++i) {
        const int rB = waveN * 64 + i * 16 + l15;
        bf[i] = *(const bf16x8*)&Bc[rB * 64 + ((cb ^ (rB & 7)) * 8)];
      }
#pragma unroll
      for (int mi = 0; mi < MI; ++mi)
#pragma unroll
        for (int ni = 0; ni < 4; ++ni)
          acc[mi][ni] = __builtin_amdgcn_mfma_f32_16x16x32_bf16(af[mi], bf[ni], acc[mi][ni], 0, 0, 0);
    }
  }

  if constexpr (MODE == 0) {
    const int which = n0 >> 9;          // block-uniform after W permutation
    const int b = m0 >> 11;
#pragma unroll
    for (int mi = 0; mi < MI; ++mi) {
#pragma unroll
      for (int ni = 0; ni < 4; ++ni) {
        const int n = n0 + waveN * 64 + ni * 16 + l15;
        const int d = n & 63, h = (n >> 6) & 7;
        const int t = (m0 & (T_ - 1)) + waveM * (TM / 2) + mi * 16 + l16 * 4;
        const size_t bh = (size_t)(b * H_ + h);
        if (which == 0) {
          bf16x4 pv;
#pragma unroll
          for (int r = 0; r < 4; ++r) pv[r] = (__bf16)(acc[mi][ni][r] * QSCALE);
          *(bf16x4*)&o0[(bh * D_ + d) * T_ + t] = pv;            // q [B,H,D,T]
        } else if (which == 1) {
#pragma unroll
          for (int r = 0; r < 4; ++r)
            o1[(bh * T_ + t + r) * D_ + d] = (__bf16)acc[mi][ni][r];  // k [B,H,T,D]
        } else {
          bf16x4 pv;
#pragma unroll
          for (int r = 0; r < 4; ++r) pv[r] = (__bf16)acc[mi][ni][r];
          *(bf16x4*)&o2[(bh * D_ + d) * T_ + t] = pv;            // v [B,H,D,T]
        }
      }
    }
  } else {
#pragma unroll
    for (int mi = 0; mi < MI; ++mi)
#pragma unroll
      for (int ni = 0; ni < 4; ++ni)
#pragma unroll
        for (int r = 0; r < 4; ++r) {
          const int m = m0 + waveM * (TM / 2) + mi * 16 + l16 * 4 + r;
          const int n = n0 + waveN * 64 + ni * 16 + l15;
          of[(size_t)m * N + n] = acc[mi][ni][r];
        }
  }
}

// Flash attention, max-free exp2-domain, 32x32x16 MFMA with IN-REGISTER P
// (no P LDS round-trip). 8 waves: tw in {0,1} = t-half(32), qq in {0..3} =
// q-slice(32). Per kt (Tk=64):
//   QK^T: sacc[16] = sum_c mfma_32x32x16(K_frag[c], Q_frag[c])  (c = d-chunk)
//     C-layout: q = lane&31, t = (reg&3) + 8*(reg>>2) + 4*(lane>>5)   [m74/m101]
//   P = exp2(sacc); pack pairs -> 8 bf16x2 words; 8 shfl_xor(32) + selects
//     rebuild the PV A-fragments (lane holds P-row for q=lane&31), zero LDS.
//   PV: oacc[dh] += mfma_32x32x16(paf[s], V_frag[s][dh])  (s = t-slab, dh = d-half)
//   l: 16 in-register adds + 1 shfl_xor(32) at the end (no ones-MFMA).
// K/V double-buffered (R0-style waitcnt(0) + syncthreads; kt&1 constant-folds
// under unroll 2 so all LDS addresses hoist out of the loop).
__global__ __launch_bounds__(512, 4)
void attn_kernel(const __bf16* __restrict__ Q, const __bf16* __restrict__ Kk,
                 const __bf16* __restrict__ Vt, __bf16* __restrict__ Out) {
  __shared__ __align__(16) char smem[37888];
  // Ks[2]: 0, 8192 ([64 t][64 d] swizzled). Vts[2]: 16384, 24576 ([64 d][64 t]).
  float* Osh = (float*)smem;               // overlay: [4 qq][64 d][36] f32 (36864 B)
  float* Lsh = (float*)(smem + 36864);     // overlay: [2 tw][4 qq][32 q] f32 (1024 B)

  const int tid = threadIdx.x, wave = tid >> 6, lane = tid & 63;
  const int l31 = lane & 31, h = lane >> 5;
  const int tw = wave >> 2, qq = wave & 3;
  const int bh  = blockIdx.y;
  const int t0q = blockIdx.x * 128;
  const __bf16* qptr = Q  + (size_t)bh * D_ * T_;   // [D][T], pre-scaled
  const __bf16* kptr = Kk + (size_t)bh * T_ * D_;   // [T][D]
  const __bf16* vptr = Vt + (size_t)bh * D_ * T_;   // [D][T]

  // Q B-frags: qf[c][j] = Q[d = c*16 + h*8 + j][q = t0q + qq*32 + l31]
  bf16x8 qf[4];
#pragma unroll
  for (int c = 0; c < 4; ++c)
#pragma unroll
    for (int j = 0; j < 8; ++j)
      qf[c][j] = qptr[(size_t)(c * 16 + h * 8 + j) * T_ + t0q + qq * 32 + l31];

  f32x16 oacc[2] = {};
  float lacc = 0.f;

  const int srow = lane >> 3;
  const int sch  = (lane & 7) ^ srow;

  // each wave stages one 8-row K slab + one 8-row V slab (2 loads/wave/tile)
  auto stage = [&](int buf, int t0k) {
    __bf16* Kd = (__bf16*)(smem + buf * 8192);
    __bf16* Vd = (__bf16*)(smem + 16384 + buf * 8192);
    const int row = wave * 8;
    async_ld16(kptr + (size_t)(t0k + row + srow) * D_ + sch * 8, Kd + row * 64);
    async_ld16(vptr + (size_t)(row + srow) * T_ + t0k + sch * 8, Vd + row * 64);
  };

  const int rt = tw * 32 + l31;            // K row (t) for QK A-frags
  stage(0, 0);
#pragma unroll 2
  for (int kt = 0; kt < 32; ++kt) {
    __builtin_amdgcn_s_waitcnt(0);
    __syncthreads();
    if (kt < 31) stage((kt + 1) & 1, (kt + 1) * 64);
    const __bf16* Ksc = (const __bf16*)(smem + (kt & 1) * 8192);
    const __bf16* Vtc = (const __bf16*)(smem + 16384 + (kt & 1) * 8192);

    // ---- QK^T: S^T[t][q], 4 chained MFMAs over d-chunks of 16 ----
    f32x16 sacc = {};
    {
      bf16x8 af[4];
#pragma unroll
      for (int c = 0; c < 4; ++c) {
        const int cb = c * 2 + h;
        af[c] = *(const bf16x8*)&Ksc[rt * 64 + ((cb ^ (rt & 7)) * 8)];
      }
      __builtin_amdgcn_s_setprio(1);
#pragma unroll
      for (int c = 0; c < 4; ++c)
        sacc = __builtin_amdgcn_mfma_f32_32x32x16_bf16(af[c], qf[c], sacc, 0, 0, 0);
      __builtin_amdgcn_s_setprio(0);
    }

    // ---- P = exp2(S), row-sum into lacc, pack to bf16x2 words ----
    float p[16];
#pragma unroll
    for (int r = 0; r < 16; ++r) {
      p[r] = __builtin_amdgcn_exp2f(sacc[r]);
      lacc += p[r];
    }
    uint w[8];
#pragma unroll
    for (int i = 0; i < 8; ++i) {
      union { __bf16 b[2]; uint u; } cv;
      cv.b[0] = (__bf16)p[2 * i]; cv.b[1] = (__bf16)p[2 * i + 1];
      w[i] = cv.u;
    }
    // word i covers t-pair {G(i), G(i)+1} + 4h, G = (i&1)*2 + (i>>1)*8.
    // Rebuild A-frags (lane needs t = s*16 + h*8 + j for its q row):
    //   pairs (0,2),(1,3),(4,6),(5,7); partner = lane^32.
    uint fw[8];
#pragma unroll
    for (int pr = 0; pr < 4; ++pr) {
      const int a = (pr & 1) + (pr >> 1) * 4;      // 0,1,4,5
      const int b = a + 2;                         // 2,3,6,7
      const uint xa = (uint)__shfl_xor((int)w[a], 32, 64);
      const uint xb = (uint)__shfl_xor((int)w[b], 32, 64);
      fw[a] = h ? xb   : w[a];
      fw[b] = h ? w[b] : xa;
    }
    bf16x8 paf[2];
    {
      union { uint u[4]; bf16x8 v; } f0, f1;
#pragma unroll
      for (int i = 0; i < 4; ++i) { f0.u[i] = fw[i]; f1.u[i] = fw[4 + i]; }
      paf[0] = f0.v; paf[1] = f1.v;
    }

    // ---- PV: O[q][d] += P-row * V, 2 t-slabs x 2 d-halves ----
    {
      bf16x8 vf[2][2];
#pragma unroll
      for (int s = 0; s < 2; ++s)
#pragma unroll
        for (int dh = 0; dh < 2; ++dh) {
          const int rdv = dh * 32 + l31;           // V row (d)
          const int ct  = tw * 4 + s * 2 + h;      // t-chunk of 8
          vf[s][dh] = *(const bf16x8*)&Vtc[rdv * 64 + ((ct ^ (rdv & 7)) * 8)];
        }
      __builtin_amdgcn_s_setprio(1);
#pragma unroll
      for (int s = 0; s < 2; ++s)
#pragma unroll
        for (int dh = 0; dh < 2; ++dh)
          oacc[dh] = __builtin_amdgcn_mfma_f32_32x32x16_bf16(paf[s], vf[s][dh], oacc[dh], 0, 0, 0);
      __builtin_amdgcn_s_setprio(0);
    }
  }

  // combine the two lane-halves of l (each lane then holds sum over this
  // wave's full 32 t for q = l31)
  lacc += __shfl_xor(lacc, 32, 64);

  // ---- cross-tw reduction + normalize + store ----
  __syncthreads();                         // all K/V LDS reads done; Osh overlay safe
  if (h == 0) Lsh[tw * 128 + qq * 32 + l31] = lacc;
  if (tw == 1) {
    float* Ow = Osh + qq * 64 * 36;
#pragma unroll
    for (int dh = 0; dh < 2; ++dh) {
      const int d = dh * 32 + l31;
#pragma unroll
      for (int g = 0; g < 4; ++g) {
        f32x4 q4;
#pragma unroll
        for (int r = 0; r < 4; ++r) q4[r] = oacc[dh][g * 4 + r];
        *(f32x4*)&Ow[d * 36 + g * 8 + 4 * h] = q4;   // q_hat = g*8 + 4h + r
      }
    }
  }
  __syncthreads();
  if (tw == 0) {
    const int b = bh >> 3, hcol = (bh & 7) * D_;
    float* Ow = Osh + qq * 64 * 36;
#pragma unroll
    for (int g = 0; g < 4; ++g) {
      const f32x4 l0 = *(const f32x4*)&Lsh[qq * 32 + g * 8 + 4 * h];
      const f32x4 l1 = *(const f32x4*)&Lsh[128 + qq * 32 + g * 8 + 4 * h];
      f32x4 linv;
#pragma unroll
      for (int r = 0; r < 4; ++r) linv[r] = __builtin_amdgcn_rcpf(l0[r] + l1[r]);
#pragma unroll
      for (int dh = 0; dh < 2; ++dh) {
        const int d = dh * 32 + l31;
        const f32x4 op = *(const f32x4*)&Ow[d * 36 + g * 8 + 4 * h];
#pragma unroll
        for (int r = 0; r < 4; ++r) {
          const int trow = t0q + qq * 32 + g * 8 + 4 * h + r;
          Out[((size_t)b * T_ + trow) * E_ + hcol + d] =
              (__bf16)((oacc[dh][g * 4 + r] + op[r]) * linv[r]);
        }
      }
    }
  }
}

extern "C" void kernel_launch(void* const* d_in, const int* in_sizes, int n_in,
                              void* d_out, int out_size, void* d_ws, size_t ws_size,
                              hipStream_t stream) {
  const float* x    = (const float*)d_in[0];
  const float* Wqkv = (const float*)d_in[1];
  const float* W0   = (const float*)d_in[2];
  float* out = (float*)d_out;

  char* ws = (char*)d_ws;
  __bf16* xb  = (__bf16*)ws;                                    // 8192*512 bf16
  __bf16* wqb = (__bf16*)(ws + 8388608);                        // 1536*512 (permuted)
  __bf16* w0b = (__bf16*)(ws + 8388608 + 1572864);              // 512*512
  __bf16* q   = (__bf16*)(ws + 8388608 + 1572864 + 524288);     // [B,H,D,T]
  __bf16* k   = q + 4194304;                                    // [B,H,T,D]
  __bf16* v   = k + 4194304;                                    // [B,H,D,T]
  __bf16* ao  = xb;  // reuse: xb consumed by QKV GEMM before attn writes ao

  cvt_all<<<2560, 256, 0, stream>>>(x, Wqkv, W0, xb, wqb, w0b);
  gemm_bt<0, 3 * H_ * D_, 128><<<dim3(12, 64), 256, 0, stream>>>(xb, wqb, q, k, v, nullptr);
  attn_kernel<<<dim3(16, 32), 512, 0, stream>>>(q, k, v, ao);
  gemm_bt<1, E_, 64><<<dim3(4, 128), 256, 0, stream>>>(ao, w0b, nullptr, nullptr, nullptr, out);
}

// Round 4
// 151.714 us; speedup vs baseline: 1.0352x; 1.0352x over previous
//
#include <hip/hip_runtime.h>

typedef __bf16 bf16x8 __attribute__((ext_vector_type(8)));
typedef __bf16 bf16x4 __attribute__((ext_vector_type(4)));
typedef float  f32x4  __attribute__((ext_vector_type(4)));

#define B_ 4
#define T_ 2048
#define H_ 8
#define D_ 64
#define E_ 512

// q scale: D^-0.5 * log2(e)  (softmax computed in exp2 domain)
#define QSCALE 0.18033688011112042f

// async global->LDS, 16B per lane. LDS dest is wave-uniform base + lane*16.
__device__ __forceinline__ void async_ld16(const __bf16* g, __bf16* lds) {
  __builtin_amdgcn_global_load_lds((const __attribute__((address_space(1))) void*)g,
                                   (__attribute__((address_space(3))) void*)lds,
                                   16, 0, 0);
}

// converts x, W_qkv (row-permuted to [which][h][d] order), W_0
__global__ void cvt_all(const float* __restrict__ x, const float* __restrict__ wq,
                        const float* __restrict__ w0, __bf16* __restrict__ xb,
                        __bf16* __restrict__ wqb, __bf16* __restrict__ w0b) {
  long i = (long)(blockIdx.x * 256 + threadIdx.x) * 8;
  const float* src; __bf16* dst; long roff, woff;
  if (i < 4194304L)      { src = x;  dst = xb;  roff = i; woff = i; }
  else if (i < 4980736L) {
    src = wq; dst = wqb; roff = i - 4194304L;
    // src row r = h*192 + d*3 + which  ->  dst row = which*512 + h*64 + d
    const int r = (int)(roff >> 9), c = (int)(roff & 511);
    const int h = r / 192, rem = r - h * 192;
    const int d = rem / 3, which = rem - d * 3;
    woff = (long)(which * 512 + h * 64 + d) * 512 + c;
  }
  else                   { src = w0; dst = w0b; roff = i - 4980736L; woff = roff; }
  float4 a = *(const float4*)(src + roff);
  float4 b = *(const float4*)(src + roff + 4);
  bf16x8 o;
  o[0] = (__bf16)a.x; o[1] = (__bf16)a.y; o[2] = (__bf16)a.z; o[3] = (__bf16)a.w;
  o[4] = (__bf16)b.x; o[5] = (__bf16)b.y; o[6] = (__bf16)b.z; o[7] = (__bf16)b.w;
  *(bf16x8*)(dst + woff) = o;
}

// C = A(MxK) * B(NxK)^T, K=512, TMx128 tile, 4 waves, 16x16x32 bf16 MFMA.
// Double-buffered staging, one barrier per K-step.
// MODE 0 (TM=128): qkv epilogue (W pre-permuted -> which = n0>>9 block-uniform).
// MODE 1: plain fp32 store, row-major MxN.
template<int MODE, int N, int TM>
__global__ __launch_bounds__(256, 2)
void gemm_bt(const __bf16* __restrict__ A, const __bf16* __restrict__ Bm,
             __bf16* __restrict__ o0, __bf16* __restrict__ o1, __bf16* __restrict__ o2,
             float* __restrict__ of) {
  constexpr int K = 512;
  constexpr int MI = TM / 32;                 // acc tiles in m per wave
  __shared__ __bf16 As[2][TM * 64];
  __shared__ __bf16 Bs[2][128 * 64];
  const int tid  = threadIdx.x;
  const int wave = tid >> 6, lane = tid & 63;
  const int l15 = lane & 15, l16 = lane >> 4;
  const int m0 = blockIdx.y * TM, n0 = blockIdx.x * 128;
  const int waveM = wave >> 1, waveN = wave & 1;
  const int srow = lane >> 3;
  const int sch  = (lane & 7) ^ srow;

  f32x4 acc[MI][4] = {};

  const __bf16* ag = A  + (size_t)(m0 + wave * 8 + srow) * K + sch * 8;
  const __bf16* bg = Bm + (size_t)(n0 + wave * 8 + srow) * K + sch * 8;

  auto stage = [&](int buf, int k0) {
#pragma unroll
    for (int it = 0; it < TM / 32; ++it)
      async_ld16(ag + (size_t)it * 32 * K + k0, &As[buf][(it * 32 + wave * 8) * 64]);
#pragma unroll
    for (int it = 0; it < 4; ++it)
      async_ld16(bg + (size_t)it * 32 * K + k0, &Bs[buf][(it * 32 + wave * 8) * 64]);
  };

  stage(0, 0);
#pragma unroll 2
  for (int kt = 0; kt < 8; ++kt) {
    __builtin_amdgcn_s_waitcnt(0);
    __syncthreads();
    if (kt < 7) stage((kt + 1) & 1, (kt + 1) * 64);
    const __bf16* Ac = As[kt & 1];
    const __bf16* Bc = Bs[kt & 1];
#pragma unroll
    for (int ks = 0; ks < 2; ++ks) {
      bf16x8 af[MI], bf[4];
      const int cb = ks * 4 + l16;
#pragma unroll
      for (int i = 0; i < MI; ++i) {
        const int rA = waveM * (TM / 2) + i * 16 + l15;
        af[i] = *(const bf16x8*)&Ac[rA * 64 + ((cb ^ (rA & 7)) * 8)];
      }
#pragma unroll
      for (int i = 0; i < 4; ++i) {
        const int rB = waveN * 64 + i * 16 + l15;
        bf[i] = *(const bf16x8*)&Bc[rB * 64 + ((cb ^ (rB & 7)) * 8)];
      }
#pragma unroll
      for (int mi = 0; mi < MI; ++mi)
#pragma unroll
        for (int ni = 0; ni < 4; ++ni)
          acc[mi][ni] = __builtin_amdgcn_mfma_f32_16x16x32_bf16(af[mi], bf[ni], acc[mi][ni], 0, 0, 0);
    }
  }

  if constexpr (MODE == 0) {
    const int which = n0 >> 9;          // block-uniform after W permutation
    const int b = m0 >> 11;
#pragma unroll
    for (int mi = 0; mi < MI; ++mi) {
#pragma unroll
      for (int ni = 0; ni < 4; ++ni) {
        const int n = n0 + waveN * 64 + ni * 16 + l15;
        const int d = n & 63, h = (n >> 6) & 7;
        const int t = (m0 & (T_ - 1)) + waveM * (TM / 2) + mi * 16 + l16 * 4;
        const size_t bh = (size_t)(b * H_ + h);
        if (which == 0) {
          bf16x4 pv;
#pragma unroll
          for (int r = 0; r < 4; ++r) pv[r] = (__bf16)(acc[mi][ni][r] * QSCALE);
          *(bf16x4*)&o0[(bh * D_ + d) * T_ + t] = pv;            // q [B,H,D,T]
        } else if (which == 1) {
#pragma unroll
          for (int r = 0; r < 4; ++r)
            o1[(bh * T_ + t + r) * D_ + d] = (__bf16)acc[mi][ni][r];  // k [B,H,T,D]
        } else {
          bf16x4 pv;
#pragma unroll
          for (int r = 0; r < 4; ++r) pv[r] = (__bf16)acc[mi][ni][r];
          *(bf16x4*)&o2[(bh * D_ + d) * T_ + t] = pv;            // v [B,H,D,T]
        }
      }
    }
  } else {
#pragma unroll
    for (int mi = 0; mi < MI; ++mi)
#pragma unroll
      for (int ni = 0; ni < 4; ++ni)
#pragma unroll
        for (int r = 0; r < 4; ++r) {
          const int m = m0 + waveM * (TM / 2) + mi * 16 + l16 * 4 + r;
          const int n = n0 + waveN * 64 + ni * 16 + l15;
          of[(size_t)m * N + n] = acc[mi][ni][r];
        }
  }
}

// Flash attention, max-free exp2-domain (R0 structure) with a 4-slot K/V ring
// and ONE BARRIER PER 2 TILES. Phase p: waitcnt(0)+barrier, then stage tiles
// 2p+2 and 2p+3 (into the slots of tiles 2p-2/2p-1, WAR-safe: all waves passed
// the barrier => finished phase p-1), then compute tiles 2p and 2p+1 with no
// sync between them. The 2-tile inter-barrier window lets waves desynchronize
// so one wave's exp2/Ps VALU phase overlaps another's MFMA phase (the R0-R2
// counters showed both pipes ~30% with ~40% idle from barrier phase-locking).
// Waves 2x2 over (t-half 32, q-half 64).
// Ps is chunk-XOR swizzled (not padded): element P[q][t] lives at
//   q*32 + ((t>>3) ^ ((q>>1)&3))*8 + (t&7)
// -> both the bf16x4 writes and the b128 A-frag reads hit each bank group
//    exactly 2-way (lanes l15 and l15+8), which is free on gfx950 (m136).
__global__ __launch_bounds__(256, 2)
void attn_kernel(const __bf16* __restrict__ Q, const __bf16* __restrict__ Kk,
                 const __bf16* __restrict__ Vt, __bf16* __restrict__ Out) {
  __shared__ __align__(16) char smem[81920];
  // K ring[4]:  0, 8192, 16384, 24576        ([64 t][64 d] swizzled)
  // V ring[4]:  32768, 40960, 49152, 57344   ([64 d][64 t] swizzled)
  // Ps: 65536, per-wave [64 q][32 t] chunk-swizzled bf16 (4096 B each, 4 waves).
  float* Osh = (float*)smem;               // overlay: [2 q2][64 d][68] f32
  float* Lsh = (float*)(smem + 34816);     // overlay: [2 q2][64 q'] f32

  const int tid = threadIdx.x, wave = tid >> 6, lane = tid & 63;
  const int l15 = lane & 15, l16 = lane >> 4;
  const int tw = wave >> 1, q2 = wave & 1;
  const int bh  = blockIdx.y;
  const int t0q = blockIdx.x * 128;
  const __bf16* qptr = Q  + (size_t)bh * D_ * T_;   // [D][T], pre-scaled
  const __bf16* kptr = Kk + (size_t)bh * T_ * D_;   // [T][D]
  const __bf16* vptr = Vt + (size_t)bh * D_ * T_;   // [D][T]

  __bf16* Pw = (__bf16*)(smem + 65536) + wave * 2048;   // [64 q][32 t] swizzled
  const int psw = (l15 >> 1) & 3;                       // per-lane chunk XOR key

  // Q fragments (wave's 64 q-cols), from [d][t]: one-time scalar loads.
  bf16x8 qf[4][2];
#pragma unroll
  for (int ni = 0; ni < 4; ++ni)
#pragma unroll
    for (int ks = 0; ks < 2; ++ks)
#pragma unroll
      for (int j = 0; j < 8; ++j)
        qf[ni][ks][j] = qptr[(size_t)(ks * 32 + l16 * 8 + j) * T_ +
                             t0q + q2 * 64 + ni * 16 + l15];

  bf16x8 ones;
#pragma unroll
  for (int j = 0; j < 8; ++j) ones[j] = (__bf16)1.0f;

  f32x4 oacc[4][4] = {};
  f32x4 lacc[4] = {};

  const int srow = lane >> 3;
  const int sch  = (lane & 7) ^ srow;

  auto stage = [&](int buf, int t0k) {
    __bf16* Kd = (__bf16*)(smem + buf * 8192);
    __bf16* Vd = (__bf16*)(smem + 32768 + buf * 8192);
#pragma unroll
    for (int i = 0; i < 2; ++i) {
      const int row = i * 32 + wave * 8;
      async_ld16(kptr + (size_t)(t0k + row + srow) * D_ + sch * 8, Kd + row * 64);
      async_ld16(vptr + (size_t)(row + srow) * T_ + t0k + sch * 8, Vd + row * 64);
    }
  };

  // prologue: first two tiles in flight
  stage(0, 0);
  stage(1, 64);
#pragma unroll 2
  for (int p = 0; p < 16; ++p) {
    __builtin_amdgcn_s_waitcnt(0);
    __syncthreads();
    if (p < 15) {
      stage((2 * p + 2) & 3, (2 * p + 2) * 64);
      stage((2 * p + 3) & 3, (2 * p + 3) * 64);
    }
#pragma unroll
    for (int kk = 0; kk < 2; ++kk) {
      const int kt = 2 * p + kk;
      const __bf16* Ksc = (const __bf16*)(smem + (kt & 3) * 8192);
      const __bf16* Vtc = (const __bf16*)(smem + 32768 + (kt & 3) * 8192);

      // S^T[t'][q'] over wave's 32 t x 64 q (log2 domain via QSCALE)
      f32x4 sacc[2][4] = {};
#pragma unroll
      for (int ks = 0; ks < 2; ++ks) {
        bf16x8 kf[2];
        const int cb = ks * 4 + l16;
#pragma unroll
        for (int mi = 0; mi < 2; ++mi) {
          const int rt = tw * 32 + mi * 16 + l15;
          kf[mi] = *(const bf16x8*)&Ksc[rt * 64 + ((cb ^ (rt & 7)) * 8)];
        }
#pragma unroll
        for (int mi = 0; mi < 2; ++mi)
#pragma unroll
          for (int ni = 0; ni < 4; ++ni)
            sacc[mi][ni] = __builtin_amdgcn_mfma_f32_16x16x32_bf16(kf[mi], qf[ni][ks], sacc[mi][ni], 0, 0, 0);
      }

      // P = exp2(S) -> wave-private Ps, chunk-swizzled.
      // t = mi*16 + l16*4 + r  ->  chunk = mi*2 + (l16>>1), intra = (l16&1)*4 + r
#pragma unroll
      for (int ni = 0; ni < 4; ++ni)
#pragma unroll
        for (int mi = 0; mi < 2; ++mi) {
          bf16x4 pv;
#pragma unroll
          for (int r = 0; r < 4; ++r) pv[r] = (__bf16)__builtin_amdgcn_exp2f(sacc[mi][ni][r]);
          *(bf16x4*)&Pw[(ni * 16 + l15) * 32 +
                        (((mi * 2 + (l16 >> 1)) ^ psw) * 8) + (l16 & 1) * 4] = pv;
        }

      // O += P*V over wave's 32 t ; l += P*1
      // A-frag read: t = l16*8 + j -> chunk = l16, intra = j
      {
        bf16x8 pf[4], vf[4];
#pragma unroll
        for (int mq = 0; mq < 4; ++mq)
          pf[mq] = *(const bf16x8*)&Pw[(mq * 16 + l15) * 32 + ((l16 ^ psw) * 8)];
#pragma unroll
        for (int nd = 0; nd < 4; ++nd) {
          const int rd = nd * 16 + l15;
          const int ct = tw * 4 + l16;
          vf[nd] = *(const bf16x8*)&Vtc[rd * 64 + ((ct ^ (rd & 7)) * 8)];
        }
#pragma unroll
        for (int mq = 0; mq < 4; ++mq) {
#pragma unroll
          for (int nd = 0; nd < 4; ++nd)
            oacc[mq][nd] = __builtin_amdgcn_mfma_f32_16x16x32_bf16(pf[mq], vf[nd], oacc[mq][nd], 0, 0, 0);
          lacc[mq] = __builtin_amdgcn_mfma_f32_16x16x32_bf16(pf[mq], ones, lacc[mq], 0, 0, 0);
        }
      }
    }
  }

  // reduce O,l across t-halves; epilogue O/l -> [B,T,H*D] bf16
  __syncthreads();
  if (tw == 1) {
    float* Ow = Osh + q2 * 4352;            // [64 d][68] f32
#pragma unroll
    for (int mq = 0; mq < 4; ++mq)
#pragma unroll
      for (int nd = 0; nd < 4; ++nd)
        *(f32x4*)&Ow[(nd * 16 + l15) * 68 + mq * 16 + l16 * 4] = oacc[mq][nd];
    if (l15 == 0)
#pragma unroll
      for (int mq = 0; mq < 4; ++mq)
        *(f32x4*)&Lsh[q2 * 64 + mq * 16 + l16 * 4] = lacc[mq];
  }
  __syncthreads();
  if (tw == 0) {
    const int b = bh >> 3, hcol = (bh & 7) * D_;
    float* Ow = Osh + q2 * 4352;
#pragma unroll
    for (int mq = 0; mq < 4; ++mq) {
      const f32x4 lv = *(const f32x4*)&Lsh[q2 * 64 + mq * 16 + l16 * 4];
      f32x4 linv;
#pragma unroll
      for (int r = 0; r < 4; ++r) linv[r] = __builtin_amdgcn_rcpf(lacc[mq][r] + lv[r]);
#pragma unroll
      for (int nd = 0; nd < 4; ++nd) {
        const f32x4 op = *(const f32x4*)&Ow[(nd * 16 + l15) * 68 + mq * 16 + l16 * 4];
#pragma unroll
        for (int r = 0; r < 4; ++r) {
          const int trow = t0q + q2 * 64 + mq * 16 + l16 * 4 + r;
          Out[((size_t)b * T_ + trow) * E_ + hcol + nd * 16 + l15] =
              (__bf16)((oacc[mq][nd][r] + op[r]) * linv[r]);
        }
      }
    }
  }
}

extern "C" void kernel_launch(void* const* d_in, const int* in_sizes, int n_in,
                              void* d_out, int out_size, void* d_ws, size_t ws_size,
                              hipStream_t stream) {
  const float* x    = (const float*)d_in[0];
  const float* Wqkv = (const float*)d_in[1];
  const float* W0   = (const float*)d_in[2];
  float* out = (float*)d_out;

  char* ws = (char*)d_ws;
  __bf16* xb  = (__bf16*)ws;                                    // 8192*512 bf16
  __bf16* wqb = (__bf16*)(ws + 8388608);                        // 1536*512 (permuted)
  __bf16* w0b = (__bf16*)(ws + 8388608 + 1572864);              // 512*512
  __bf16* q   = (__bf16*)(ws + 8388608 + 1572864 + 524288);     // [B,H,D,T]
  __bf16* k   = q + 4194304;                                    // [B,H,T,D]
  __bf16* v   = k + 4194304;                                    // [B,H,D,T]
  __bf16* ao  = xb;  // reuse: xb consumed by QKV GEMM before attn writes ao

  cvt_all<<<2560, 256, 0, stream>>>(x, Wqkv, W0, xb, wqb, w0b);
  gemm_bt<0, 3 * H_ * D_, 128><<<dim3(12, 64), 256, 0, stream>>>(xb, wqb, q, k, v, nullptr);
  attn_kernel<<<dim3(16, 32), 256, 0, stream>>>(q, k, v, ao);
  gemm_bt<1, E_, 64><<<dim3(4, 128), 256, 0, stream>>>(ao, w0b, nullptr, nullptr, nullptr, out);
}

// Round 5
// 150.754 us; speedup vs baseline: 1.0418x; 1.0064x over previous
//
#include <hip/hip_runtime.h>

typedef __bf16 bf16x8 __attribute__((ext_vector_type(8)));
typedef __bf16 bf16x4 __attribute__((ext_vector_type(4)));
typedef float  f32x4  __attribute__((ext_vector_type(4)));

#define B_ 4
#define T_ 2048
#define H_ 8
#define D_ 64
#define E_ 512

// q scale: D^-0.5 * log2(e)  (softmax computed in exp2 domain)
#define QSCALE 0.18033688011112042f

// async global->LDS, 16B per lane. LDS dest is wave-uniform base + lane*16.
__device__ __forceinline__ void async_ld16(const __bf16* g, __bf16* lds) {
  __builtin_amdgcn_global_load_lds((const __attribute__((address_space(1))) void*)g,
                                   (__attribute__((address_space(3))) void*)lds,
                                   16, 0, 0);
}

// converts x, W_qkv (row-permuted to [which][h][d] order), W_0
__global__ void cvt_all(const float* __restrict__ x, const float* __restrict__ wq,
                        const float* __restrict__ w0, __bf16* __restrict__ xb,
                        __bf16* __restrict__ wqb, __bf16* __restrict__ w0b) {
  long i = (long)(blockIdx.x * 256 + threadIdx.x) * 8;
  const float* src; __bf16* dst; long roff, woff;
  if (i < 4194304L)      { src = x;  dst = xb;  roff = i; woff = i; }
  else if (i < 4980736L) {
    src = wq; dst = wqb; roff = i - 4194304L;
    // src row r = h*192 + d*3 + which  ->  dst row = which*512 + h*64 + d
    const int r = (int)(roff >> 9), c = (int)(roff & 511);
    const int h = r / 192, rem = r - h * 192;
    const int d = rem / 3, which = rem - d * 3;
    woff = (long)(which * 512 + h * 64 + d) * 512 + c;
  }
  else                   { src = w0; dst = w0b; roff = i - 4980736L; woff = roff; }
  float4 a = *(const float4*)(src + roff);
  float4 b = *(const float4*)(src + roff + 4);
  bf16x8 o;
  o[0] = (__bf16)a.x; o[1] = (__bf16)a.y; o[2] = (__bf16)a.z; o[3] = (__bf16)a.w;
  o[4] = (__bf16)b.x; o[5] = (__bf16)b.y; o[6] = (__bf16)b.z; o[7] = (__bf16)b.w;
  *(bf16x8*)(dst + woff) = o;
}

// C = A(MxK) * B(NxK)^T, K=512, TMx128 tile, 4 waves, 16x16x32 bf16 MFMA.
// BK=32, 3-slot LDS ring, prefetch depth 2, counted vmcnt (T3/T4): at the top
// of step s we drain ONLY stage(s)'s loads (vmcnt(LPW)), keeping stage(s+1)'s
// in flight across the barrier; stage(s+2) is issued AFTER the barrier
// (WAR-safe: slot (s+2)%3 == (s-1)%3 whose readers all passed the barrier).
// LDS 48 KB (TM=128 -> 3 blocks/CU) / 36 KB (TM=64 -> 4 blocks/CU).
// LDS swizzle for 64-B rows: chunk ^= (row>>1)&3, applied identically to the
// pre-swizzled global source (linear gload_lds dest) and the ds_read (rule:
// both-sides-or-neither). b128 reads land 2-way per bank group (free, m136).
// MODE 0 (TM=128): qkv epilogue (W pre-permuted -> which = n0>>9 block-uniform).
// MODE 1: plain fp32 store, row-major MxN.
template<int MODE, int N, int TM>
__global__ __launch_bounds__(256, TM == 128 ? 3 : 4)
void gemm_bt(const __bf16* __restrict__ A, const __bf16* __restrict__ Bm,
             __bf16* __restrict__ o0, __bf16* __restrict__ o1, __bf16* __restrict__ o2,
             float* __restrict__ of) {
  constexpr int K = 512;
  constexpr int MI = TM / 32;                 // acc tiles in m per wave
  constexpr int AL = TM / 64;                 // A slab-loads per wave per stage
  __shared__ __bf16 As[3][TM * 32];
  __shared__ __bf16 Bs[3][128 * 32];
  const int tid  = threadIdx.x;
  const int wave = tid >> 6, lane = tid & 63;
  const int l15 = lane & 15, l16 = lane >> 4;
  const int m0 = blockIdx.y * TM, n0 = blockIdx.x * 128;
  const int waveM = wave >> 1, waveN = wave & 1;
  // staging lane map: 16-row slab of 32 cols (64 B/row); lane -> (row, chunk)
  //   row = lane>>2, slot-chunk = lane&3, global-chunk = (lane&3) ^ key(row),
  //   key(row) = (row>>1)&3 == (lane>>3)&3  (slab base is a multiple of 16).
  const int lr  = lane >> 2;
  const int lc8 = ((lane & 3) ^ ((lane >> 3) & 3)) * 8;

  f32x4 acc[MI][4] = {};

  const __bf16* ag = A  + (size_t)(m0 + wave * (AL * 16) + lr) * K + lc8;
  const __bf16* bg = Bm + (size_t)(n0 + wave * 32 + lr) * K + lc8;

  auto stage = [&](int buf, int k0) {
#pragma unroll
    for (int it = 0; it < AL; ++it)
      async_ld16(ag + (size_t)it * 16 * K + k0, &As[buf][(wave * AL + it) * 512]);
#pragma unroll
    for (int it = 0; it < 2; ++it)
      async_ld16(bg + (size_t)it * 16 * K + k0, &Bs[buf][(wave * 2 + it) * 512]);
  };

  stage(0, 0);
  stage(1, 32);
#pragma unroll
  for (int s = 0; s < 16; ++s) {
    if (s == 15) {
      asm volatile("s_waitcnt vmcnt(0)" ::: "memory");
    } else {
      if constexpr (AL == 2) asm volatile("s_waitcnt vmcnt(4)" ::: "memory");
      else                   asm volatile("s_waitcnt vmcnt(3)" ::: "memory");
    }
    __builtin_amdgcn_s_barrier();
    if (s < 14) stage((s + 2) % 3, (s + 2) * 32);
    const __bf16* Ac = As[s % 3];
    const __bf16* Bc = Bs[s % 3];
    bf16x8 af[MI], bfr[4];
#pragma unroll
    for (int i = 0; i < MI; ++i) {
      const int rA = waveM * (TM / 2) + i * 16 + l15;
      af[i] = *(const bf16x8*)&Ac[rA * 32 + ((l16 ^ ((rA >> 1) & 3)) * 8)];
    }
#pragma unroll
    for (int i = 0; i < 4; ++i) {
      const int rB = waveN * 64 + i * 16 + l15;
      bfr[i] = *(const bf16x8*)&Bc[rB * 32 + ((l16 ^ ((rB >> 1) & 3)) * 8)];
    }
#pragma unroll
    for (int mi = 0; mi < MI; ++mi)
#pragma unroll
      for (int ni = 0; ni < 4; ++ni)
        acc[mi][ni] = __builtin_amdgcn_mfma_f32_16x16x32_bf16(af[mi], bfr[ni], acc[mi][ni], 0, 0, 0);
  }

  if constexpr (MODE == 0) {
    const int which = n0 >> 9;          // block-uniform after W permutation
    const int b = m0 >> 11;
#pragma unroll
    for (int mi = 0; mi < MI; ++mi) {
#pragma unroll
      for (int ni = 0; ni < 4; ++ni) {
        const int n = n0 + waveN * 64 + ni * 16 + l15;
        const int d = n & 63, h = (n >> 6) & 7;
        const int t = (m0 & (T_ - 1)) + waveM * (TM / 2) + mi * 16 + l16 * 4;
        const size_t bh = (size_t)(b * H_ + h);
        if (which == 0) {
          bf16x4 pv;
#pragma unroll
          for (int r = 0; r < 4; ++r) pv[r] = (__bf16)(acc[mi][ni][r] * QSCALE);
          *(bf16x4*)&o0[(bh * D_ + d) * T_ + t] = pv;            // q [B,H,D,T]
        } else if (which == 1) {
#pragma unroll
          for (int r = 0; r < 4; ++r)
            o1[(bh * T_ + t + r) * D_ + d] = (__bf16)acc[mi][ni][r];  // k [B,H,T,D]
        } else {
          bf16x4 pv;
#pragma unroll
          for (int r = 0; r < 4; ++r) pv[r] = (__bf16)acc[mi][ni][r];
          *(bf16x4*)&o2[(bh * D_ + d) * T_ + t] = pv;            // v [B,H,D,T]
        }
      }
    }
  } else {
#pragma unroll
    for (int mi = 0; mi < MI; ++mi)
#pragma unroll
      for (int ni = 0; ni < 4; ++ni)
#pragma unroll
        for (int r = 0; r < 4; ++r) {
          const int m = m0 + waveM * (TM / 2) + mi * 16 + l16 * 4 + r;
          const int n = n0 + waveN * 64 + ni * 16 + l15;
          of[(size_t)m * N + n] = acc[mi][ni][r];
        }
  }
}

// Flash attention, max-free exp2-domain (R0 structure) with a 4-slot K/V ring
// and ONE BARRIER PER 2 TILES (best measured attn: 48.1 us). Phase p:
// waitcnt(0)+barrier, stage tiles 2p+2/2p+3 (WAR-safe), compute tiles 2p,2p+1
// with no sync between them. Waves 2x2 over (t-half 32, q-half 64).
// Ps is chunk-XOR swizzled: element P[q][t] lives at
//   q*32 + ((t>>3) ^ ((q>>1)&3))*8 + (t&7)  -> 2-way max on write+read (free).
__global__ __launch_bounds__(256, 2)
void attn_kernel(const __bf16* __restrict__ Q, const __bf16* __restrict__ Kk,
                 const __bf16* __restrict__ Vt, __bf16* __restrict__ Out) {
  __shared__ __align__(16) char smem[81920];
  // K ring[4]:  0, 8192, 16384, 24576        ([64 t][64 d] swizzled)
  // V ring[4]:  32768, 40960, 49152, 57344   ([64 d][64 t] swizzled)
  // Ps: 65536, per-wave [64 q][32 t] chunk-swizzled bf16 (4096 B each, 4 waves).
  float* Osh = (float*)smem;               // overlay: [2 q2][64 d][68] f32
  float* Lsh = (float*)(smem + 34816);     // overlay: [2 q2][64 q'] f32

  const int tid = threadIdx.x, wave = tid >> 6, lane = tid & 63;
  const int l15 = lane & 15, l16 = lane >> 4;
  const int tw = wave >> 1, q2 = wave & 1;
  const int bh  = blockIdx.y;
  const int t0q = blockIdx.x * 128;
  const __bf16* qptr = Q  + (size_t)bh * D_ * T_;   // [D][T], pre-scaled
  const __bf16* kptr = Kk + (size_t)bh * T_ * D_;   // [T][D]
  const __bf16* vptr = Vt + (size_t)bh * D_ * T_;   // [D][T]

  __bf16* Pw = (__bf16*)(smem + 65536) + wave * 2048;   // [64 q][32 t] swizzled
  const int psw = (l15 >> 1) & 3;                       // per-lane chunk XOR key

  // Q fragments (wave's 64 q-cols), from [d][t]: one-time scalar loads.
  bf16x8 qf[4][2];
#pragma unroll
  for (int ni = 0; ni < 4; ++ni)
#pragma unroll
    for (int ks = 0; ks < 2; ++ks)
#pragma unroll
      for (int j = 0; j < 8; ++j)
        qf[ni][ks][j] = qptr[(size_t)(ks * 32 + l16 * 8 + j) * T_ +
                             t0q + q2 * 64 + ni * 16 + l15];

  bf16x8 ones;
#pragma unroll
  for (int j = 0; j < 8; ++j) ones[j] = (__bf16)1.0f;

  f32x4 oacc[4][4] = {};
  f32x4 lacc[4] = {};

  const int srow = lane >> 3;
  const int sch  = (lane & 7) ^ srow;

  auto stage = [&](int buf, int t0k) {
    __bf16* Kd = (__bf16*)(smem + buf * 8192);
    __bf16* Vd = (__bf16*)(smem + 32768 + buf * 8192);
#pragma unroll
    for (int i = 0; i < 2; ++i) {
      const int row = i * 32 + wave * 8;
      async_ld16(kptr + (size_t)(t0k + row + srow) * D_ + sch * 8, Kd + row * 64);
      async_ld16(vptr + (size_t)(row + srow) * T_ + t0k + sch * 8, Vd + row * 64);
    }
  };

  // prologue: first two tiles in flight
  stage(0, 0);
  stage(1, 64);
#pragma unroll 2
  for (int p = 0; p < 16; ++p) {
    __builtin_amdgcn_s_waitcnt(0);
    __syncthreads();
    if (p < 15) {
      stage((2 * p + 2) & 3, (2 * p + 2) * 64);
      stage((2 * p + 3) & 3, (2 * p + 3) * 64);
    }
#pragma unroll
    for (int kk = 0; kk < 2; ++kk) {
      const int kt = 2 * p + kk;
      const __bf16* Ksc = (const __bf16*)(smem + (kt & 3) * 8192);
      const __bf16* Vtc = (const __bf16*)(smem + 32768 + (kt & 3) * 8192);

      // S^T[t'][q'] over wave's 32 t x 64 q (log2 domain via QSCALE)
      f32x4 sacc[2][4] = {};
#pragma unroll
      for (int ks = 0; ks < 2; ++ks) {
        bf16x8 kf[2];
        const int cb = ks * 4 + l16;
#pragma unroll
        for (int mi = 0; mi < 2; ++mi) {
          const int rt = tw * 32 + mi * 16 + l15;
          kf[mi] = *(const bf16x8*)&Ksc[rt * 64 + ((cb ^ (rt & 7)) * 8)];
        }
#pragma unroll
        for (int mi = 0; mi < 2; ++mi)
#pragma unroll
          for (int ni = 0; ni < 4; ++ni)
            sacc[mi][ni] = __builtin_amdgcn_mfma_f32_16x16x32_bf16(kf[mi], qf[ni][ks], sacc[mi][ni], 0, 0, 0);
      }

      // P = exp2(S) -> wave-private Ps, chunk-swizzled.
      // t = mi*16 + l16*4 + r  ->  chunk = mi*2 + (l16>>1), intra = (l16&1)*4 + r
#pragma unroll
      for (int ni = 0; ni < 4; ++ni)
#pragma unroll
        for (int mi = 0; mi < 2; ++mi) {
          bf16x4 pv;
#pragma unroll
          for (int r = 0; r < 4; ++r) pv[r] = (__bf16)__builtin_amdgcn_exp2f(sacc[mi][ni][r]);
          *(bf16x4*)&Pw[(ni * 16 + l15) * 32 +
                        (((mi * 2 + (l16 >> 1)) ^ psw) * 8) + (l16 & 1) * 4] = pv;
        }

      // O += P*V over wave's 32 t ; l += P*1
      // A-frag read: t = l16*8 + j -> chunk = l16, intra = j
      {
        bf16x8 pf[4], vf[4];
#pragma unroll
        for (int mq = 0; mq < 4; ++mq)
          pf[mq] = *(const bf16x8*)&Pw[(mq * 16 + l15) * 32 + ((l16 ^ psw) * 8)];
#pragma unroll
        for (int nd = 0; nd < 4; ++nd) {
          const int rd = nd * 16 + l15;
          const int ct = tw * 4 + l16;
          vf[nd] = *(const bf16x8*)&Vtc[rd * 64 + ((ct ^ (rd & 7)) * 8)];
        }
#pragma unroll
        for (int mq = 0; mq < 4; ++mq) {
#pragma unroll
          for (int nd = 0; nd < 4; ++nd)
            oacc[mq][nd] = __builtin_amdgcn_mfma_f32_16x16x32_bf16(pf[mq], vf[nd], oacc[mq][nd], 0, 0, 0);
          lacc[mq] = __builtin_amdgcn_mfma_f32_16x16x32_bf16(pf[mq], ones, lacc[mq], 0, 0, 0);
        }
      }
    }
  }

  // reduce O,l across t-halves; epilogue O/l -> [B,T,H*D] bf16
  __syncthreads();
  if (tw == 1) {
    float* Ow = Osh + q2 * 4352;            // [64 d][68] f32
#pragma unroll
    for (int mq = 0; mq < 4; ++mq)
#pragma unroll
      for (int nd = 0; nd < 4; ++nd)
        *(f32x4*)&Ow[(nd * 16 + l15) * 68 + mq * 16 + l16 * 4] = oacc[mq][nd];
    if (l15 == 0)
#pragma unroll
      for (int mq = 0; mq < 4; ++mq)
        *(f32x4*)&Lsh[q2 * 64 + mq * 16 + l16 * 4] = lacc[mq];
  }
  __syncthreads();
  if (tw == 0) {
    const int b = bh >> 3, hcol = (bh & 7) * D_;
    float* Ow = Osh + q2 * 4352;
#pragma unroll
    for (int mq = 0; mq < 4; ++mq) {
      const f32x4 lv = *(const f32x4*)&Lsh[q2 * 64 + mq * 16 + l16 * 4];
      f32x4 linv;
#pragma unroll
      for (int r = 0; r < 4; ++r) linv[r] = __builtin_amdgcn_rcpf(lacc[mq][r] + lv[r]);
#pragma unroll
      for (int nd = 0; nd < 4; ++nd) {
        const f32x4 op = *(const f32x4*)&Ow[(nd * 16 + l15) * 68 + mq * 16 + l16 * 4];
#pragma unroll
        for (int r = 0; r < 4; ++r) {
          const int trow = t0q + q2 * 64 + mq * 16 + l16 * 4 + r;
          Out[((size_t)b * T_ + trow) * E_ + hcol + nd * 16 + l15] =
              (__bf16)((oacc[mq][nd][r] + op[r]) * linv[r]);
        }
      }
    }
  }
}

extern "C" void kernel_launch(void* const* d_in, const int* in_sizes, int n_in,
                              void* d_out, int out_size, void* d_ws, size_t ws_size,
                              hipStream_t stream) {
  const float* x    = (const float*)d_in[0];
  const float* Wqkv = (const float*)d_in[1];
  const float* W0   = (const float*)d_in[2];
  float* out = (float*)d_out;

  char* ws = (char*)d_ws;
  __bf16* xb  = (__bf16*)ws;                                    // 8192*512 bf16
  __bf16* wqb = (__bf16*)(ws + 8388608);                        // 1536*512 (permuted)
  __bf16* w0b = (__bf16*)(ws + 8388608 + 1572864);              // 512*512
  __bf16* q   = (__bf16*)(ws + 8388608 + 1572864 + 524288);     // [B,H,D,T]
  __bf16* k   = q + 4194304;                                    // [B,H,T,D]
  __bf16* v   = k + 4194304;                                    // [B,H,D,T]
  __bf16* ao  = xb;  // reuse: xb consumed by QKV GEMM before attn writes ao

  cvt_all<<<2560, 256, 0, stream>>>(x, Wqkv, W0, xb, wqb, w0b);
  gemm_bt<0, 3 * H_ * D_, 128><<<dim3(12, 64), 256, 0, stream>>>(xb, wqb, q, k, v, nullptr);
  attn_kernel<<<dim3(16, 32), 256, 0, stream>>>(q, k, v, ao);
  gemm_bt<1, E_, 64><<<dim3(4, 128), 256, 0, stream>>>(ao, w0b, nullptr, nullptr, nullptr, out);
}